// Round 4
// baseline (141.816 us; speedup 1.0000x reference)
//
#include <hip/hip_runtime.h>
#include <hip/hip_bf16.h>
#include <cstdint>
#include <cstddef>

typedef float  f32x4  __attribute__((ext_vector_type(4)));
typedef __bf16 bf16x8 __attribute__((ext_vector_type(8)));
typedef __bf16 bf16x4 __attribute__((ext_vector_type(4)));

#define MFMA(a, b, c) __builtin_amdgcn_mfma_f32_16x16x32_bf16((a), (b), (c), 0, 0, 0)

#define B_     8
#define S_     2048
#define D_     1024
#define E_     64
#define YSZ    (B_ * S_ * D_)   // 16777216
#define KTR    16               // truncation depth: rho^16 ~ 2e-7

// ---------------- k_setup: convert weights to bf16 ----------------
__global__ __launch_bounds__(256) void k_setup(const float* __restrict__ w_in,
                                               const float* __restrict__ w_out,
                                               __bf16* __restrict__ winb,
                                               __bf16* __restrict__ wob) {
  const int i = blockIdx.x * 256 + threadIdx.x;
  winb[i] = (__bf16)w_in[i];
  wob[i]  = (__bf16)w_out[i];
}

// ---------------- k_bi: beta GEMM (blocks 0..255) || impulse (block 256) ----------------
// 512 threads. Beta blocks: 64 rows x 64 e, 8 waves = 4 row-groups x 2 e-halves;
// per-wave acc[2] (16 rows x 32 e) keeps VGPR ~90 (no spill). Per-block kk rotation
// de-floods winb L2 lines. Impulse block: waves 0-3 validated machinery, waves 4-7
// barrier-match.
__global__ __launch_bounds__(512, 4) void k_bi(const float* __restrict__ x,
                                               const __bf16* __restrict__ winb,
                                               const float* __restrict__ resonance,
                                               const float* __restrict__ alpha,
                                               const float* __restrict__ omega,
                                               __bf16* __restrict__ beta_bf,
                                               __bf16* __restrict__ Gt,
                                               float* __restrict__ CkTR,
                                               float* __restrict__ CkTI) {
  __shared__ __bf16 lsr[4][16][72];
  __shared__ __bf16 lsi[4][16][72];

  const int tid = threadIdx.x;
  const int w = tid >> 6, lane = tid & 63;
  const int u = lane >> 4, fl = lane & 15;

  if (blockIdx.x < 256) {
    // ---- beta GEMM ----
    const int rg = w >> 1, eh = w & 1;
    const int rot = blockIdx.x & 15;
    const int rowA = blockIdx.x * 64 + rg * 16 + fl;
    const float*  xp = x + (size_t)rowA * 1024 + u * 8;
    const __bf16* wp = winb + (size_t)(eh * 32 + fl) * 1024 + u * 8;

    f32x4  acc[2] = {};
    f32x4  xc[2][2], xn[2][2];
    bf16x8 bc[2][2], bn[2][2];

    {
      const int kr = rot;   // kk = 0
#pragma unroll
      for (int kt = 0; kt < 2; kt++) {
        xc[kt][0] = *(const f32x4*)(xp + kr * 64 + kt * 32);
        xc[kt][1] = *(const f32x4*)(xp + kr * 64 + kt * 32 + 4);
      }
#pragma unroll
      for (int et = 0; et < 2; et++)
#pragma unroll
        for (int kt = 0; kt < 2; kt++)
          bc[et][kt] = *(const bf16x8*)(wp + et * 16384 + kr * 64 + kt * 32);
    }

#pragma unroll
    for (int kk = 0; kk < 16; kk++) {
      if (kk < 15) {
        const int kr = (kk + 1 + rot) & 15;
#pragma unroll
        for (int kt = 0; kt < 2; kt++) {
          xn[kt][0] = *(const f32x4*)(xp + kr * 64 + kt * 32);
          xn[kt][1] = *(const f32x4*)(xp + kr * 64 + kt * 32 + 4);
        }
#pragma unroll
        for (int et = 0; et < 2; et++)
#pragma unroll
          for (int kt = 0; kt < 2; kt++)
            bn[et][kt] = *(const bf16x8*)(wp + et * 16384 + kr * 64 + kt * 32);
      }
      bf16x8 af[2];
#pragma unroll
      for (int kt = 0; kt < 2; kt++)
#pragma unroll
        for (int j = 0; j < 4; j++) {
          af[kt][j]     = (__bf16)xc[kt][0][j];
          af[kt][j + 4] = (__bf16)xc[kt][1][j];
        }
#pragma unroll
      for (int et = 0; et < 2; et++) {
        acc[et] = MFMA(af[0], bc[et][0], acc[et]);
        acc[et] = MFMA(af[1], bc[et][1], acc[et]);
      }
      if (kk < 15) {
#pragma unroll
        for (int kt = 0; kt < 2; kt++) { xc[kt][0] = xn[kt][0]; xc[kt][1] = xn[kt][1]; }
#pragma unroll
        for (int et = 0; et < 2; et++) { bc[et][0] = bn[et][0]; bc[et][1] = bn[et][1]; }
      }
    }

    const int rowC = blockIdx.x * 64 + rg * 16 + u * 4;
#pragma unroll
    for (int et = 0; et < 2; et++)
#pragma unroll
      for (int r = 0; r < 4; r++)
        beta_bf[(size_t)(rowC + r) * 64 + eh * 32 + et * 16 + fl] = (__bf16)acc[et][r];
    return;
  }

  // ---- impulse block: waves 4-7 just match barriers ----
  if (tid >= 256) {
    for (int s = 0; s < KTR; s++) { __syncthreads(); __syncthreads(); }
    return;
  }

  const int ecol = w * 16 + fl;   // wave w (0..3) owns impulse columns w*16..+15

  bf16x8 afr[4][2];   // A[f][e] = R[e][f] - (e==f)
#pragma unroll
  for (int mt = 0; mt < 4; mt++)
#pragma unroll
    for (int kt = 0; kt < 2; kt++)
#pragma unroll
      for (int j = 0; j < 8; j++) {
        const int e = kt * 32 + u * 8 + j;
        const int f = mt * 16 + fl;
        float v = resonance[e * 64 + f];
        if (e == f) v -= 1.0f;
        afr[mt][kt][j] = (__bf16)v;
      }

  float mcv[4][4], msv[4][4];
#pragma unroll
  for (int mt = 0; mt < 4; mt++)
#pragma unroll
    for (int r = 0; r < 4; r++) {
      const int fr = mt * 16 + u * 4 + r;
      const float mg = 1.0f / (1.0f + expf(-alpha[fr]));
      mcv[mt][r] = mg * cosf(omega[fr]);
      msv[mt][r] = mg * sinf(omega[fr]);
    }

  f32x4 sr[4] = {}, si[4] = {};

  for (int s = 0; s < KTR; s++) {
    f32x4 rr[4], ri[4];
#pragma unroll
    for (int mt = 0; mt < 4; mt++)
#pragma unroll
      for (int r = 0; r < 4; r++) {
        const float bt = (s == 0 && (mt * 16 + u * 4 + r) == ecol) ? 1.0f : 0.0f;
        rr[mt][r] = mcv[mt][r] * sr[mt][r] - msv[mt][r] * si[mt][r] + bt;
        ri[mt][r] = msv[mt][r] * sr[mt][r] + mcv[mt][r] * si[mt][r];
      }
#pragma unroll
    for (int mt = 0; mt < 4; mt++) {
      bf16x4 pr, pi;
#pragma unroll
      for (int r = 0; r < 4; r++) { pr[r] = (__bf16)rr[mt][r]; pi[r] = (__bf16)ri[mt][r]; }
      *(bf16x4*)&lsr[w][fl][mt * 16 + u * 4] = pr;
      *(bf16x4*)&lsi[w][fl][mt * 16 + u * 4] = pi;
    }
    __syncthreads();
    bf16x8 brf[2], bif[2];
#pragma unroll
    for (int kt = 0; kt < 2; kt++) {
      brf[kt] = *(const bf16x8*)&lsr[w][fl][kt * 32 + u * 8];
      bif[kt] = *(const bf16x8*)&lsi[w][fl][kt * 32 + u * 8];
    }
#pragma unroll
    for (int mt = 0; mt < 4; mt++) {
      f32x4 dr = MFMA(afr[mt][0], brf[0], rr[mt]);
      sr[mt]   = MFMA(afr[mt][1], brf[1], dr);
      f32x4 di = MFMA(afr[mt][0], bif[0], ri[mt]);
      si[mt]   = MFMA(afr[mt][1], bif[1], di);
    }
#pragma unroll
    for (int mt = 0; mt < 4; mt++)
#pragma unroll
      for (int r = 0; r < 4; r++) {
        const int f = mt * 16 + u * 4 + r;
        Gt[f * 1024 + s * 64 + ecol]    = (__bf16)sr[mt][r];
        CkTR[s * 4096 + ecol * 64 + f]  = sr[mt][r];
        CkTI[s * 4096 + ecol * 64 + f]  = si[mt][r];
      }
    __syncthreads();
  }
}

// ---------------- k_cy: conv (LDS halo) + y GEMM + LN; fin on blocks 0..7 ----------------
// 520 blocks x 512 thr. Main blocks (8..519): 32 rows x 1024 cols.
// Stage beta halo (48x64, zero-padded) in LDS -> conv A via ds_read, no select chain.
// Conv: 8 waves = 2 rowg x 4 fg, acc = 1x f32x4. Y: wave owns 32 rows x 128 cols,
// acc[2][8] = 64 VGPR (static-indexed; rotation address-only). LN across 8 waves.
__global__ __launch_bounds__(512, 4) void k_cy(const __bf16* __restrict__ beta_bf,
                                               const __bf16* __restrict__ Gt,
                                               const __bf16* __restrict__ wob,
                                               const float* __restrict__ gamma,
                                               const float* __restrict__ lbeta,
                                               const float* __restrict__ CkTR,
                                               const float* __restrict__ CkTI,
                                               float* __restrict__ y) {
  __shared__ __bf16 bhalo[48][72];
  __shared__ __bf16 st[32][72];
  __shared__ float pS1[8][32];
  __shared__ float pS2[8][32];

  const int tid = threadIdx.x;
  const int w = tid >> 6, lane = tid & 63;
  const int u = lane >> 4, fl = lane & 15;

  if (blockIdx.x < 8) {   // fin blocks: no barriers, dispatched first
    if (tid < 64) {
      const int b = blockIdx.x;
      const int f = tid;
      float aR = 0.f, aI = 0.f;
#pragma unroll
      for (int k = 0; k < KTR; k++) {
        const __bf16* br = beta_bf + (size_t)(b * S_ + (S_ - 1) - k) * 64;
        const float* cR = CkTR + k * 4096 + f;
        const float* cI = CkTI + k * 4096 + f;
#pragma unroll
        for (int e = 0; e < 64; e += 4) {
          const float b0 = (float)br[e],     b1 = (float)br[e + 1];
          const float b2 = (float)br[e + 2], b3 = (float)br[e + 3];
          aR += b0 * cR[e * 64] + b1 * cR[(e + 1) * 64] + b2 * cR[(e + 2) * 64] + b3 * cR[(e + 3) * 64];
          aI += b0 * cI[e * 64] + b1 * cI[(e + 1) * 64] + b2 * cI[(e + 2) * 64] + b3 * cI[(e + 3) * 64];
        }
      }
      y[YSZ + b * 64 + f]       = aR;
      y[YSZ + 512 + b * 64 + f] = aI;
    }
    return;
  }

  const int bid = blockIdx.x - 8;
  const int rowbase = bid * 32;
  const int tloc = rowbase & (S_ - 1);

  // ---- stage beta halo: rows rowbase-16 .. rowbase+31, zeroed where t<0 ----
  if (tid < 384) {
    const int hr = tid >> 3, off = (tid & 7) * 8;
    bf16x8 v = {};
    if (tloc + hr - 16 >= 0)
      v = *(const bf16x8*)(beta_bf + (size_t)(rowbase + hr - 16) * 64 + off);
    *(bf16x8*)&bhalo[hr][off] = v;
  }
  __syncthreads();

  // ---- conv: states = sum_k beta[t-k] @ G_k ----
  {
    const int rg = w & 1, fg = w >> 1;
    const int rot = bid & 15;
    const __bf16* gp = Gt + (size_t)(fg * 16 + fl) * 1024 + u * 8;

    f32x4 acc = {};
    bf16x8 bq[2][2];
    {
      const int kr = rot;
      bq[0][0] = *(const bf16x8*)(gp + kr * 64);
      bq[0][1] = *(const bf16x8*)(gp + kr * 64 + 32);
    }
#pragma unroll
    for (int kk = 0; kk < 16; kk++) {
      const int p = kk & 1;
      const int kr = (kk + rot) & 15;
      if (kk < 15) {
        const int krn = (kk + 1 + rot) & 15;
        bq[p ^ 1][0] = *(const bf16x8*)(gp + krn * 64);
        bq[p ^ 1][1] = *(const bf16x8*)(gp + krn * 64 + 32);
      }
      const int arow = 16 + rg * 16 + fl - kr;
      const bf16x8 a0 = *(const bf16x8*)&bhalo[arow][u * 8];
      const bf16x8 a1 = *(const bf16x8*)&bhalo[arow][32 + u * 8];
      acc = MFMA(a0, bq[p][0], acc);
      acc = MFMA(a1, bq[p][1], acc);
    }
#pragma unroll
    for (int r = 0; r < 4; r++)
      st[rg * 16 + u * 4 + r][fg * 16 + fl] = (__bf16)acc[r];
  }
  __syncthreads();

  // ---- y = states @ w_out^T + LN ----
  bf16x8 ar[2][2];
#pragma unroll
  for (int rt = 0; rt < 2; rt++)
#pragma unroll
    for (int kt = 0; kt < 2; kt++)
      ar[rt][kt] = *(const bf16x8*)&st[rt * 16 + fl][kt * 32 + u * 8];

  const int rot2 = bid & 7;
  f32x4 acc[2][8] = {};
  bf16x8 bq[2][2];
  {
    const int ctr = rot2;
    const __bf16* wp2 = wob + (size_t)(w * 128 + ctr * 16 + fl) * 64 + u * 8;
    bq[0][0] = *(const bf16x8*)(wp2);
    bq[0][1] = *(const bf16x8*)(wp2 + 32);
  }
#pragma unroll
  for (int ct = 0; ct < 8; ct++) {
    const int p = ct & 1;
    if (ct < 7) {
      const int ctr = (ct + 1 + rot2) & 7;
      const __bf16* wp2 = wob + (size_t)(w * 128 + ctr * 16 + fl) * 64 + u * 8;
      bq[p ^ 1][0] = *(const bf16x8*)(wp2);
      bq[p ^ 1][1] = *(const bf16x8*)(wp2 + 32);
    }
    acc[0][ct] = MFMA(ar[0][0], bq[p][0], acc[0][ct]);
    acc[0][ct] = MFMA(ar[0][1], bq[p][1], acc[0][ct]);
    acc[1][ct] = MFMA(ar[1][0], bq[p][0], acc[1][ct]);
    acc[1][ct] = MFMA(ar[1][1], bq[p][1], acc[1][ct]);
  }

  // per-row partial sums over this wave's 128 cols
  float s1[2][4], s2[2][4];
#pragma unroll
  for (int rt = 0; rt < 2; rt++)
#pragma unroll
    for (int r = 0; r < 4; r++) {
      float a = 0.f, q = 0.f;
#pragma unroll
      for (int ct = 0; ct < 8; ct++) {
        const float v = acc[rt][ct][r];
        a += v; q += v * v;
      }
      s1[rt][r] = a; s2[rt][r] = q;
    }
#pragma unroll
  for (int m = 1; m < 16; m <<= 1) {
#pragma unroll
    for (int rt = 0; rt < 2; rt++)
#pragma unroll
      for (int r = 0; r < 4; r++) {
        s1[rt][r] += __shfl_xor(s1[rt][r], m, 64);
        s2[rt][r] += __shfl_xor(s2[rt][r], m, 64);
      }
  }
  if (fl == 0) {
#pragma unroll
    for (int rt = 0; rt < 2; rt++)
#pragma unroll
      for (int r = 0; r < 4; r++) {
        pS1[w][rt * 16 + u * 4 + r] = s1[rt][r];
        pS2[w][rt * 16 + u * 4 + r] = s2[rt][r];
      }
  }
  __syncthreads();
  float mu[2][4], rs[2][4];
#pragma unroll
  for (int rt = 0; rt < 2; rt++)
#pragma unroll
    for (int r = 0; r < 4; r++) {
      const int rl = rt * 16 + u * 4 + r;
      float S1 = 0.f, S2 = 0.f;
#pragma unroll
      for (int ww = 0; ww < 8; ww++) { S1 += pS1[ww][rl]; S2 += pS2[ww][rl]; }
      const float m  = S1 * (1.0f / 1024.0f);
      const float va = S2 * (1.0f / 1024.0f) - m * m;
      mu[rt][r] = m;
      rs[rt][r] = rsqrtf(va + 1e-5f);
    }
#pragma unroll
  for (int ct = 0; ct < 8; ct++) {
    const int ctr = (ct + rot2) & 7;
    const int d = w * 128 + ctr * 16 + fl;
    const float gv = gamma[d], bv = lbeta[d];
#pragma unroll
    for (int rt = 0; rt < 2; rt++)
#pragma unroll
      for (int r = 0; r < 4; r++) {
        const float v = (acc[rt][ct][r] - mu[rt][r]) * rs[rt][r] * gv + bv;
        y[(size_t)(rowbase + rt * 16 + u * 4 + r) * 1024 + d] = v;
      }
  }
}

extern "C" void kernel_launch(void* const* d_in, const int* in_sizes, int n_in,
                              void* d_out, int out_size, void* d_ws, size_t ws_size,
                              hipStream_t stream) {
  const float* x         = (const float*)d_in[0];
  const float* alpha     = (const float*)d_in[1];
  const float* omega     = (const float*)d_in[2];
  const float* w_in      = (const float*)d_in[3];
  const float* w_out     = (const float*)d_in[4];
  const float* resonance = (const float*)d_in[5];
  const float* ln_g      = (const float*)d_in[6];
  const float* ln_b      = (const float*)d_in[7];
  float* out = (float*)d_out;

  char* ws = (char*)d_ws;
  __bf16* beta_bf = (__bf16*)ws;                                   // 2 MB
  __bf16* winb    = (__bf16*)(ws + (2u << 20));                    // 128 KB
  __bf16* wob     = (__bf16*)(ws + (2u << 20) + (128u << 10));     // 128 KB
  __bf16* Gt      = (__bf16*)(ws + (2u << 20) + (256u << 10));     // 128 KB
  float*  CkTR    = (float*) (ws + (2u << 20) + (384u << 10));     // 256 KB
  float*  CkTI    = (float*) (ws + (2u << 20) + (640u << 10));     // 256 KB

  k_setup<<<256, 256, 0, stream>>>(w_in, w_out, winb, wob);
  k_bi   <<<257, 512, 0, stream>>>(x, winb, resonance, alpha, omega,
                                   beta_bf, Gt, CkTR, CkTI);
  k_cy   <<<520, 512, 0, stream>>>(beta_bf, Gt, wob, ln_g, ln_b, CkTR, CkTI, out);
}

// Round 5
// 118.283 us; speedup vs baseline: 1.1990x; 1.1990x over previous
//
#include <hip/hip_runtime.h>
#include <hip/hip_bf16.h>
#include <cstdint>
#include <cstddef>

typedef float  f32x4  __attribute__((ext_vector_type(4)));
typedef __bf16 bf16x8 __attribute__((ext_vector_type(8)));
typedef __bf16 bf16x4 __attribute__((ext_vector_type(4)));

#define MFMA(a, b, c) __builtin_amdgcn_mfma_f32_16x16x32_bf16((a), (b), (c), 0, 0, 0)

#define B_     8
#define S_     2048
#define D_     1024
#define E_     64
#define YSZ    (B_ * S_ * D_)   // 16777216
#define KTR    16               // truncation depth: rho^16 ~ 2e-7

// ---------------- k_setup: convert weights to bf16 ----------------
__global__ __launch_bounds__(256) void k_setup(const float* __restrict__ w_in,
                                               const float* __restrict__ w_out,
                                               __bf16* __restrict__ winb,
                                               __bf16* __restrict__ wob) {
  const int i = blockIdx.x * 256 + threadIdx.x;
  winb[i] = (__bf16)w_in[i];
  wob[i]  = (__bf16)w_out[i];
}

// ---------------- k_bi2: beta GEMM (blocks 0..255) || impulse (blocks 256..259) ----------------
// Beta path: R1-validated k_beta verbatim (f32 out, acc[4], 256 thr, no VGPR cap).
// Impulse path: ONE wave per block (R2-validated shape), NO barriers (within-wave
// LDS RAW handled by compiler lgkmcnt) -> no spill, ~6 us, hidden under beta.
__global__ __launch_bounds__(256) void k_bi2(const float* __restrict__ x,
                                             const __bf16* __restrict__ winb,
                                             const float* __restrict__ resonance,
                                             const float* __restrict__ alpha,
                                             const float* __restrict__ omega,
                                             float* __restrict__ beta,
                                             __bf16* __restrict__ Gt,
                                             float* __restrict__ CkTR,
                                             float* __restrict__ CkTI) {
  __shared__ __bf16 lsr[16][72];
  __shared__ __bf16 lsi[16][72];

  const int tid = threadIdx.x;

  if (blockIdx.x < 256) {
    // ---- beta GEMM (R1 verbatim) ----
    const int w = tid >> 6, lane = tid & 63;
    const int u = lane >> 4, fl = lane & 15;
    const int rowA = blockIdx.x * 64 + w * 16 + fl;
    const float*  xp = x + (size_t)rowA * 1024 + u * 8;
    const __bf16* wp = winb + fl * 1024 + u * 8;

    f32x4  acc[4] = {};
    f32x4  xc[2][2], xn[2][2];
    bf16x8 bc[4][2], bn[4][2];

#pragma unroll
    for (int kt = 0; kt < 2; kt++) {
      xc[kt][0] = *(const f32x4*)(xp + kt * 32);
      xc[kt][1] = *(const f32x4*)(xp + kt * 32 + 4);
    }
#pragma unroll
    for (int ct = 0; ct < 4; ct++)
#pragma unroll
      for (int kt = 0; kt < 2; kt++)
        bc[ct][kt] = *(const bf16x8*)(wp + ct * 16384 + kt * 32);

#pragma unroll
    for (int kk = 0; kk < 16; kk++) {
      if (kk < 15) {
        const int k1 = (kk + 1) * 64;
#pragma unroll
        for (int kt = 0; kt < 2; kt++) {
          xn[kt][0] = *(const f32x4*)(xp + k1 + kt * 32);
          xn[kt][1] = *(const f32x4*)(xp + k1 + kt * 32 + 4);
        }
#pragma unroll
        for (int ct = 0; ct < 4; ct++)
#pragma unroll
          for (int kt = 0; kt < 2; kt++)
            bn[ct][kt] = *(const bf16x8*)(wp + ct * 16384 + k1 + kt * 32);
      }
      bf16x8 af[2];
#pragma unroll
      for (int kt = 0; kt < 2; kt++)
#pragma unroll
        for (int j = 0; j < 4; j++) {
          af[kt][j]     = (__bf16)xc[kt][0][j];
          af[kt][j + 4] = (__bf16)xc[kt][1][j];
        }
#pragma unroll
      for (int ct = 0; ct < 4; ct++) {
        acc[ct] = MFMA(af[0], bc[ct][0], acc[ct]);
        acc[ct] = MFMA(af[1], bc[ct][1], acc[ct]);
      }
      if (kk < 15) {
#pragma unroll
        for (int kt = 0; kt < 2; kt++) { xc[kt][0] = xn[kt][0]; xc[kt][1] = xn[kt][1]; }
#pragma unroll
        for (int ct = 0; ct < 4; ct++) { bc[ct][0] = bn[ct][0]; bc[ct][1] = bn[ct][1]; }
      }
    }

    const int rowC = blockIdx.x * 64 + w * 16 + u * 4;
#pragma unroll
    for (int ct = 0; ct < 4; ct++)
#pragma unroll
      for (int r = 0; r < 4; r++)
        beta[(size_t)(rowC + r) * 64 + ct * 16 + fl] = acc[ct][r];
    return;
  }

  // ---- impulse: C_k = R(LambdaR)^k; one wave, 16 impulse columns per block ----
  if (tid >= 64) return;
  const int lane = tid;
  const int u = lane >> 4, fl = lane & 15;
  const int ecol = (blockIdx.x - 256) * 16 + fl;

  bf16x8 afr[4][2];   // A[f][e] = R[e][f] - (e==f)
#pragma unroll
  for (int mt = 0; mt < 4; mt++)
#pragma unroll
    for (int kt = 0; kt < 2; kt++)
#pragma unroll
      for (int j = 0; j < 8; j++) {
        const int e = kt * 32 + u * 8 + j;
        const int f = mt * 16 + fl;
        float v = resonance[e * 64 + f];
        if (e == f) v -= 1.0f;
        afr[mt][kt][j] = (__bf16)v;
      }

  float mcv[4][4], msv[4][4];
#pragma unroll
  for (int mt = 0; mt < 4; mt++)
#pragma unroll
    for (int r = 0; r < 4; r++) {
      const int fr = mt * 16 + u * 4 + r;
      const float mg = 1.0f / (1.0f + expf(-alpha[fr]));
      mcv[mt][r] = mg * cosf(omega[fr]);
      msv[mt][r] = mg * sinf(omega[fr]);
    }

  f32x4 sr[4] = {}, si[4] = {};

  for (int s = 0; s < KTR; s++) {
    f32x4 rr[4], ri[4];
#pragma unroll
    for (int mt = 0; mt < 4; mt++)
#pragma unroll
      for (int r = 0; r < 4; r++) {
        const float bt = (s == 0 && (mt * 16 + u * 4 + r) == ecol) ? 1.0f : 0.0f;
        rr[mt][r] = mcv[mt][r] * sr[mt][r] - msv[mt][r] * si[mt][r] + bt;
        ri[mt][r] = msv[mt][r] * sr[mt][r] + mcv[mt][r] * si[mt][r];
      }
#pragma unroll
    for (int mt = 0; mt < 4; mt++) {
      bf16x4 pr, pi;
#pragma unroll
      for (int r = 0; r < 4; r++) { pr[r] = (__bf16)rr[mt][r]; pi[r] = (__bf16)ri[mt][r]; }
      *(bf16x4*)&lsr[fl][mt * 16 + u * 4] = pr;
      *(bf16x4*)&lsi[fl][mt * 16 + u * 4] = pi;
    }
    // single wave: compiler-inserted lgkmcnt orders ds_write -> ds_read; no barrier
    bf16x8 brf[2], bif[2];
#pragma unroll
    for (int kt = 0; kt < 2; kt++) {
      brf[kt] = *(const bf16x8*)&lsr[fl][kt * 32 + u * 8];
      bif[kt] = *(const bf16x8*)&lsi[fl][kt * 32 + u * 8];
    }
#pragma unroll
    for (int mt = 0; mt < 4; mt++) {
      f32x4 dr = MFMA(afr[mt][0], brf[0], rr[mt]);
      sr[mt]   = MFMA(afr[mt][1], brf[1], dr);
      f32x4 di = MFMA(afr[mt][0], bif[0], ri[mt]);
      si[mt]   = MFMA(afr[mt][1], bif[1], di);
    }
    // state now equals C_s; store (Gt for conv, CkT [k][e][f] for coalesced fin)
#pragma unroll
    for (int mt = 0; mt < 4; mt++)
#pragma unroll
      for (int r = 0; r < 4; r++) {
        const int f = mt * 16 + u * 4 + r;
        Gt[f * 1024 + s * 64 + ecol]   = (__bf16)sr[mt][r];
        CkTR[s * 4096 + ecol * 64 + f] = sr[mt][r];
        CkTI[s * 4096 + ecol * 64 + f] = si[mt][r];
      }
  }
}

// ---------------- k_cf: conv (blocks 0..255, R2 verbatim) || fin (blocks 256..263) ----------------
__global__ __launch_bounds__(256) void k_cf(const float* __restrict__ beta,
                                            const __bf16* __restrict__ Gt,
                                            const float* __restrict__ CkTR,
                                            const float* __restrict__ CkTI,
                                            __bf16* __restrict__ states,
                                            float* __restrict__ outp) {
  const int tid = threadIdx.x;

  if (blockIdx.x < 256) {
    // ---- conv: states[t] = sum_k beta[t-k] @ G_k (banded-Toeplitz GEMM, R2 verbatim) ----
    const int w = tid >> 6, lane = tid & 63;
    const int u = lane >> 4, fl = lane & 15;
    const int rowA = blockIdx.x * 64 + w * 16 + fl;
    const int tloc = rowA & (S_ - 1);
    const float*  xp = beta + (size_t)rowA * 64 + u * 8;
    const __bf16* wp = Gt + fl * 1024 + u * 8;
    const f32x4 Z = {0.f, 0.f, 0.f, 0.f};

    f32x4  acc[4] = {};
    f32x4  xc[2][2], xn[2][2];
    bf16x8 bc[4][2], bn[4][2];

#pragma unroll
    for (int kt = 0; kt < 2; kt++) {
      xc[kt][0] = *(const f32x4*)(xp + kt * 32);
      xc[kt][1] = *(const f32x4*)(xp + kt * 32 + 4);
    }
#pragma unroll
    for (int ct = 0; ct < 4; ct++)
#pragma unroll
      for (int kt = 0; kt < 2; kt++)
        bc[ct][kt] = *(const bf16x8*)(wp + ct * 16384 + kt * 32);

#pragma unroll
    for (int kk = 0; kk < 16; kk++) {
      if (kk < 15) {
        const int k1 = kk + 1;
        const bool ok = (tloc >= k1);
        const float* ap = xp - (ok ? k1 * 64 : 0);
#pragma unroll
        for (int kt = 0; kt < 2; kt++) {
          f32x4 v0 = *(const f32x4*)(ap + kt * 32);
          f32x4 v1 = *(const f32x4*)(ap + kt * 32 + 4);
          xn[kt][0] = ok ? v0 : Z;
          xn[kt][1] = ok ? v1 : Z;
        }
#pragma unroll
        for (int ct = 0; ct < 4; ct++)
#pragma unroll
          for (int kt = 0; kt < 2; kt++)
            bn[ct][kt] = *(const bf16x8*)(wp + ct * 16384 + k1 * 64 + kt * 32);
      }
      bf16x8 af[2];
#pragma unroll
      for (int kt = 0; kt < 2; kt++)
#pragma unroll
        for (int j = 0; j < 4; j++) {
          af[kt][j]     = (__bf16)xc[kt][0][j];
          af[kt][j + 4] = (__bf16)xc[kt][1][j];
        }
#pragma unroll
      for (int ct = 0; ct < 4; ct++) {
        acc[ct] = MFMA(af[0], bc[ct][0], acc[ct]);
        acc[ct] = MFMA(af[1], bc[ct][1], acc[ct]);
      }
      if (kk < 15) {
#pragma unroll
        for (int kt = 0; kt < 2; kt++) { xc[kt][0] = xn[kt][0]; xc[kt][1] = xn[kt][1]; }
#pragma unroll
        for (int ct = 0; ct < 4; ct++) { bc[ct][0] = bn[ct][0]; bc[ct][1] = bn[ct][1]; }
      }
    }

    const int rowC = blockIdx.x * 64 + w * 16 + u * 4;
#pragma unroll
    for (int ct = 0; ct < 4; ct++)
#pragma unroll
      for (int r = 0; r < 4; r++)
        states[(size_t)(rowC + r) * 64 + ct * 16 + fl] = (__bf16)acc[ct][r];
    return;
  }

  // ---- fin: r_fin/i_fin = sum_k beta[2047-k] @ C_k; coalesced CkT[k][e][f] reads ----
  if (tid >= 64) return;
  const int b = blockIdx.x - 256;
  const int f = tid;
  float aR = 0.f, aI = 0.f;
#pragma unroll
  for (int k = 0; k < KTR; k++) {
    const float* br = beta + (size_t)(b * S_ + (S_ - 1) - k) * 64;
    const float* cR = CkTR + k * 4096 + f;
    const float* cI = CkTI + k * 4096 + f;
#pragma unroll
    for (int e = 0; e < 64; e++) {
      const float bv = br[e];          // wave-uniform -> scalar load
      aR += bv * cR[e * 64];           // lanes f: contiguous 256B, coalesced
      aI += bv * cI[e * 64];
    }
  }
  outp[YSZ + b * 64 + f]       = aR;
  outp[YSZ + 512 + b * 64 + f] = aI;
}

// ---------------- k_y2: y = states @ w_out^T + LayerNorm, spill-free ----------------
// 512 blocks x 512 thr; block = 32 rows x 1024 cols. Wave w: rowg=w&1 (16 rows),
// colg=w>>1 (256 cols). acc[16] f32x4 = 64 VGPR; peak live ~110 -> no spill.
__global__ __launch_bounds__(512) void k_y2(const __bf16* __restrict__ states,
                                            const __bf16* __restrict__ wob,
                                            const float* __restrict__ gamma,
                                            const float* __restrict__ lbeta,
                                            float* __restrict__ y) {
  __shared__ float pS1[8][16];
  __shared__ float pS2[8][16];

  const int tid = threadIdx.x;
  const int w = tid >> 6, lane = tid & 63;
  const int u = lane >> 4, fl = lane & 15;
  const int rowg = w & 1, colg = w >> 1;
  const int rowbase = blockIdx.x * 32;

  bf16x8 ar[2];
#pragma unroll
  for (int kt = 0; kt < 2; kt++)
    ar[kt] = *(const bf16x8*)(states + (size_t)(rowbase + rowg * 16 + fl) * 64 + kt * 32 + u * 8);

  const __bf16* wp = wob + (size_t)(colg * 256 + fl) * 64 + u * 8;  // + ct*1024 + kt*32

  f32x4 acc[16] = {};
  bf16x8 bq[2][2];
  bq[0][0] = *(const bf16x8*)(wp);
  bq[0][1] = *(const bf16x8*)(wp + 32);

#pragma unroll
  for (int ct = 0; ct < 16; ct++) {
    const int p = ct & 1;
    if (ct < 15) {
      const __bf16* wpn = wp + (ct + 1) * 1024;
      bq[p ^ 1][0] = *(const bf16x8*)(wpn);
      bq[p ^ 1][1] = *(const bf16x8*)(wpn + 32);
    }
    acc[ct] = MFMA(ar[0], bq[p][0], acc[ct]);
    acc[ct] = MFMA(ar[1], bq[p][1], acc[ct]);
  }

  // LN partials over this wave's 256 cols
  float s1[4], s2[4];
#pragma unroll
  for (int r = 0; r < 4; r++) {
    float a = 0.f, q = 0.f;
#pragma unroll
    for (int ct = 0; ct < 16; ct++) {
      const float v = acc[ct][r];
      a += v; q += v * v;
    }
    s1[r] = a; s2[r] = q;
  }
#pragma unroll
  for (int m = 1; m < 16; m <<= 1) {
#pragma unroll
    for (int r = 0; r < 4; r++) {
      s1[r] += __shfl_xor(s1[r], m, 64);
      s2[r] += __shfl_xor(s2[r], m, 64);
    }
  }
  if (fl == 0) {
#pragma unroll
    for (int r = 0; r < 4; r++) {
      pS1[w][u * 4 + r] = s1[r];
      pS2[w][u * 4 + r] = s2[r];
    }
  }
  __syncthreads();

  float mu[4], rs[4];
#pragma unroll
  for (int r = 0; r < 4; r++) {
    const int rl = u * 4 + r;
    float S1 = 0.f, S2 = 0.f;
#pragma unroll
    for (int cg = 0; cg < 4; cg++) { S1 += pS1[cg * 2 + rowg][rl]; S2 += pS2[cg * 2 + rowg][rl]; }
    const float m  = S1 * (1.0f / 1024.0f);
    const float va = S2 * (1.0f / 1024.0f) - m * m;
    mu[r] = m;
    rs[r] = rsqrtf(va + 1e-5f);
  }

#pragma unroll
  for (int ct = 0; ct < 16; ct++) {
    const int d = colg * 256 + ct * 16 + fl;
    const float gv = gamma[d], bv = lbeta[d];
#pragma unroll
    for (int r = 0; r < 4; r++) {
      const float v = (acc[ct][r] - mu[r]) * rs[r] * gv + bv;
      y[(size_t)(rowbase + rowg * 16 + u * 4 + r) * 1024 + d] = v;
    }
  }
}

extern "C" void kernel_launch(void* const* d_in, const int* in_sizes, int n_in,
                              void* d_out, int out_size, void* d_ws, size_t ws_size,
                              hipStream_t stream) {
  const float* x         = (const float*)d_in[0];
  const float* alpha     = (const float*)d_in[1];
  const float* omega     = (const float*)d_in[2];
  const float* w_in      = (const float*)d_in[3];
  const float* w_out     = (const float*)d_in[4];
  const float* resonance = (const float*)d_in[5];
  const float* ln_g      = (const float*)d_in[6];
  const float* ln_b      = (const float*)d_in[7];
  float* out = (float*)d_out;

  char* ws = (char*)d_ws;
  float*  beta    = (float*)ws;                                    // 4 MB
  __bf16* states  = (__bf16*)(ws + (4u << 20));                    // 2 MB
  __bf16* winb    = (__bf16*)(ws + (6u << 20));                    // 128 KB
  __bf16* wob     = (__bf16*)(ws + (6u << 20) + (128u << 10));     // 128 KB
  __bf16* Gt      = (__bf16*)(ws + (6u << 20) + (256u << 10));     // 128 KB
  float*  CkTR    = (float*) (ws + (6u << 20) + (384u << 10));     // 256 KB
  float*  CkTI    = (float*) (ws + (6u << 20) + (640u << 10));     // 256 KB

  k_setup<<<256, 256, 0, stream>>>(w_in, w_out, winb, wob);
  k_bi2  <<<260, 256, 0, stream>>>(x, winb, resonance, alpha, omega,
                                   beta, Gt, CkTR, CkTI);
  k_cf   <<<264, 256, 0, stream>>>(beta, Gt, CkTR, CkTI, states, out);
  k_y2   <<<512, 512, 0, stream>>>(states, wob, ln_g, ln_b, out);
}

// Round 6
// 108.801 us; speedup vs baseline: 1.3034x; 1.0871x over previous
//
#include <hip/hip_runtime.h>
#include <hip/hip_bf16.h>
#include <cstdint>
#include <cstddef>

typedef float  f32x4  __attribute__((ext_vector_type(4)));
typedef __bf16 bf16x8 __attribute__((ext_vector_type(8)));
typedef __bf16 bf16x4 __attribute__((ext_vector_type(4)));

#define MFMA(a, b, c) __builtin_amdgcn_mfma_f32_16x16x32_bf16((a), (b), (c), 0, 0, 0)

#define B_     8
#define S_     2048
#define D_     1024
#define E_     64
#define YSZ    (B_ * S_ * D_)   // 16777216
#define KTR    16               // truncation depth: rho^16 ~ 2e-7

// ---------------- k_su: weight bf16 conversion (blocks 0..255) || impulse (256..259) ----------------
// Impulse path: ONE wave per block, no barriers (within-wave lgkmcnt ordering),
// no VGPR cap -> no spill. ~4 us, overlapped with the conversions.
__global__ __launch_bounds__(256) void k_su(const float* __restrict__ w_in,
                                            const float* __restrict__ w_out,
                                            const float* __restrict__ resonance,
                                            const float* __restrict__ alpha,
                                            const float* __restrict__ omega,
                                            __bf16* __restrict__ winb,
                                            __bf16* __restrict__ wob,
                                            __bf16* __restrict__ Gt,
                                            float* __restrict__ CkTR,
                                            float* __restrict__ CkTI) {
  __shared__ __bf16 lsr[16][72];
  __shared__ __bf16 lsi[16][72];

  const int tid = threadIdx.x;

  if (blockIdx.x < 256) {
    const int i = blockIdx.x * 256 + tid;
    winb[i] = (__bf16)w_in[i];
    wob[i]  = (__bf16)w_out[i];
    return;
  }

  // ---- impulse: C_k = R(LambdaR)^k; one wave, 16 impulse columns per block ----
  if (tid >= 64) return;
  const int lane = tid;
  const int u = lane >> 4, fl = lane & 15;
  const int ecol = (blockIdx.x - 256) * 16 + fl;

  bf16x8 afr[4][2];   // A[f][e] = R[e][f] - (e==f)
#pragma unroll
  for (int mt = 0; mt < 4; mt++)
#pragma unroll
    for (int kt = 0; kt < 2; kt++)
#pragma unroll
      for (int j = 0; j < 8; j++) {
        const int e = kt * 32 + u * 8 + j;
        const int f = mt * 16 + fl;
        float v = resonance[e * 64 + f];
        if (e == f) v -= 1.0f;
        afr[mt][kt][j] = (__bf16)v;
      }

  float mcv[4][4], msv[4][4];
#pragma unroll
  for (int mt = 0; mt < 4; mt++)
#pragma unroll
    for (int r = 0; r < 4; r++) {
      const int fr = mt * 16 + u * 4 + r;
      const float mg = 1.0f / (1.0f + expf(-alpha[fr]));
      mcv[mt][r] = mg * cosf(omega[fr]);
      msv[mt][r] = mg * sinf(omega[fr]);
    }

  f32x4 sr[4] = {}, si[4] = {};

  for (int s = 0; s < KTR; s++) {
    f32x4 rr[4], ri[4];
#pragma unroll
    for (int mt = 0; mt < 4; mt++)
#pragma unroll
      for (int r = 0; r < 4; r++) {
        const float bt = (s == 0 && (mt * 16 + u * 4 + r) == ecol) ? 1.0f : 0.0f;
        rr[mt][r] = mcv[mt][r] * sr[mt][r] - msv[mt][r] * si[mt][r] + bt;
        ri[mt][r] = msv[mt][r] * sr[mt][r] + mcv[mt][r] * si[mt][r];
      }
#pragma unroll
    for (int mt = 0; mt < 4; mt++) {
      bf16x4 pr, pi;
#pragma unroll
      for (int r = 0; r < 4; r++) { pr[r] = (__bf16)rr[mt][r]; pi[r] = (__bf16)ri[mt][r]; }
      *(bf16x4*)&lsr[fl][mt * 16 + u * 4] = pr;
      *(bf16x4*)&lsi[fl][mt * 16 + u * 4] = pi;
    }
    bf16x8 brf[2], bif[2];
#pragma unroll
    for (int kt = 0; kt < 2; kt++) {
      brf[kt] = *(const bf16x8*)&lsr[fl][kt * 32 + u * 8];
      bif[kt] = *(const bf16x8*)&lsi[fl][kt * 32 + u * 8];
    }
#pragma unroll
    for (int mt = 0; mt < 4; mt++) {
      f32x4 dr = MFMA(afr[mt][0], brf[0], rr[mt]);
      sr[mt]   = MFMA(afr[mt][1], brf[1], dr);
      f32x4 di = MFMA(afr[mt][0], bif[0], ri[mt]);
      si[mt]   = MFMA(afr[mt][1], bif[1], di);
    }
#pragma unroll
    for (int mt = 0; mt < 4; mt++)
#pragma unroll
      for (int r = 0; r < 4; r++) {
        const int f = mt * 16 + u * 4 + r;
        Gt[f * 1024 + s * 64 + ecol]   = (__bf16)sr[mt][r];
        CkTR[s * 4096 + ecol * 64 + f] = sr[mt][r];
        CkTI[s * 4096 + ecol * 64 + f] = si[mt][r];
      }
  }
}

// ---------------- k_b: beta = bf16(x @ w_in^T), K-split across 4 waves ----------------
// 1024 blocks x 256 thr = 4096 waves (3-4/SIMD -> latency hidden). Block = 16 rows;
// wave w handles K-quarter [w*256, w*256+256) as 4 kk-steps of 64. Partials reduced
// via 16 KB LDS, then bf16 store. x prefetched 1-deep (HBM stream); winb loaded
// in-loop (L2-hot). ~110 live VGPR -> no spill without any launch_bounds min-waves.
__global__ __launch_bounds__(256) void k_b(const float* __restrict__ x,
                                           const __bf16* __restrict__ winb,
                                           __bf16* __restrict__ beta_bf) {
  __shared__ float red[4][16][64];

  const int tid = threadIdx.x;
  const int w = tid >> 6, lane = tid & 63;
  const int u = lane >> 4, fl = lane & 15;
  const int rowA = blockIdx.x * 16 + fl;
  const float*  xp = x + (size_t)rowA * 1024 + w * 256 + u * 8;
  const __bf16* wp = winb + (size_t)fl * 1024 + w * 256 + u * 8;

  f32x4 acc[4] = {};
  f32x4 xc[2][2], xn[2][2];

#pragma unroll
  for (int kt = 0; kt < 2; kt++) {
    xc[kt][0] = *(const f32x4*)(xp + kt * 32);
    xc[kt][1] = *(const f32x4*)(xp + kt * 32 + 4);
  }

#pragma unroll
  for (int kk = 0; kk < 4; kk++) {
    if (kk < 3) {
      const int k1 = (kk + 1) * 64;
#pragma unroll
      for (int kt = 0; kt < 2; kt++) {
        xn[kt][0] = *(const f32x4*)(xp + k1 + kt * 32);
        xn[kt][1] = *(const f32x4*)(xp + k1 + kt * 32 + 4);
      }
    }
    bf16x8 af[2];
#pragma unroll
    for (int kt = 0; kt < 2; kt++)
#pragma unroll
      for (int j = 0; j < 4; j++) {
        af[kt][j]     = (__bf16)xc[kt][0][j];
        af[kt][j + 4] = (__bf16)xc[kt][1][j];
      }
#pragma unroll
    for (int ct = 0; ct < 4; ct++) {
      const __bf16* bp = wp + ct * 16384 + kk * 64;
      const bf16x8 b0 = *(const bf16x8*)(bp);
      const bf16x8 b1 = *(const bf16x8*)(bp + 32);
      acc[ct] = MFMA(af[0], b0, acc[ct]);
      acc[ct] = MFMA(af[1], b1, acc[ct]);
    }
    if (kk < 3) {
#pragma unroll
      for (int kt = 0; kt < 2; kt++) { xc[kt][0] = xn[kt][0]; xc[kt][1] = xn[kt][1]; }
    }
  }

  // partials -> LDS, cross-wave reduce, bf16 store
#pragma unroll
  for (int ct = 0; ct < 4; ct++)
#pragma unroll
    for (int r = 0; r < 4; r++)
      red[w][u * 4 + r][ct * 16 + fl] = acc[ct][r];
  __syncthreads();

  const int rr = tid >> 4, e0 = (tid & 15) * 4;
  f32x4 s = *(const f32x4*)&red[0][rr][e0];
  s += *(const f32x4*)&red[1][rr][e0];
  s += *(const f32x4*)&red[2][rr][e0];
  s += *(const f32x4*)&red[3][rr][e0];
  bf16x4 o;
#pragma unroll
  for (int j = 0; j < 4; j++) o[j] = (__bf16)s[j];
  *(bf16x4*)(beta_bf + (size_t)(blockIdx.x * 16 + rr) * 64 + e0) = o;
}

// ---------------- k_cfy: conv (lag-split) + y GEMM + LN (blocks 0..1023) || fin (1024..1031) ----------------
// Block = 16 seq rows x full D=1024. Phase A: wave w computes lags [w*4, w*4+4) of
// states = sum_k beta[t-k] @ G_k; partials reduced via LDS -> st[16][64] bf16 (never
// leaves LDS). Phase B: wave w = col-quarter, acc[16] (spill-free k_y2 shape) + LN
// across 4 waves. All A/B operands L2-resident; 4096 waves hide latency.
__global__ __launch_bounds__(256) void k_cfy(const __bf16* __restrict__ beta_bf,
                                             const __bf16* __restrict__ Gt,
                                             const __bf16* __restrict__ wob,
                                             const float* __restrict__ gamma,
                                             const float* __restrict__ lbeta,
                                             const float* __restrict__ CkTR,
                                             const float* __restrict__ CkTI,
                                             float* __restrict__ y) {
  __shared__ float red[4][16][64];
  __shared__ __bf16 st[16][72];
  __shared__ float pS1[4][16];
  __shared__ float pS2[4][16];

  const int tid = threadIdx.x;
  const int w = tid >> 6, lane = tid & 63;
  const int u = lane >> 4, fl = lane & 15;

  if (blockIdx.x >= 1024) {
    // ---- fin: r_fin/i_fin = sum_k beta[2047-k] @ C_k; coalesced CkT[k][e][f] ----
    if (tid >= 64) return;
    const int b = blockIdx.x - 1024;
    const int f = tid;
    float aR = 0.f, aI = 0.f;
#pragma unroll
    for (int k = 0; k < KTR; k++) {
      const __bf16* br = beta_bf + (size_t)(b * S_ + (S_ - 1) - k) * 64;
      const float* cR = CkTR + k * 4096 + f;
      const float* cI = CkTI + k * 4096 + f;
#pragma unroll
      for (int e = 0; e < 64; e++) {
        const float bv = (float)br[e];   // wave-uniform
        aR += bv * cR[e * 64];           // lanes f contiguous -> coalesced
        aI += bv * cI[e * 64];
      }
    }
    y[YSZ + b * 64 + f]       = aR;
    y[YSZ + 512 + b * 64 + f] = aI;
    return;
  }

  const int rowbase = blockIdx.x * 16;
  const int rowA = rowbase + fl;
  const int tloc = rowA & (S_ - 1);

  // ---- phase A: conv, wave w -> lags w*4 .. w*4+3 ----
  {
    const __bf16* xp = beta_bf + (size_t)rowA * 64 + u * 8;
    const bf16x8 ZB = {};
    f32x4 acc[4] = {};
#pragma unroll
    for (int kk = 0; kk < 4; kk++) {
      const int k = w * 4 + kk;
      const bool ok = (tloc >= k);
      const __bf16* ap = xp - (ok ? k * 64 : 0);
      bf16x8 t0 = *(const bf16x8*)(ap);
      bf16x8 t1 = *(const bf16x8*)(ap + 32);
      const bf16x8 a0 = ok ? t0 : ZB;
      const bf16x8 a1 = ok ? t1 : ZB;
#pragma unroll
      for (int ct = 0; ct < 4; ct++) {
        const __bf16* gp = Gt + (size_t)(ct * 16 + fl) * 1024 + k * 64 + u * 8;
        const bf16x8 b0 = *(const bf16x8*)(gp);
        const bf16x8 b1 = *(const bf16x8*)(gp + 32);
        acc[ct] = MFMA(a0, b0, acc[ct]);
        acc[ct] = MFMA(a1, b1, acc[ct]);
      }
    }
#pragma unroll
    for (int ct = 0; ct < 4; ct++)
#pragma unroll
      for (int r = 0; r < 4; r++)
        red[w][u * 4 + r][ct * 16 + fl] = acc[ct][r];
  }
  __syncthreads();
  {
    const int rr = tid >> 4, e0 = (tid & 15) * 4;
    f32x4 s = *(const f32x4*)&red[0][rr][e0];
    s += *(const f32x4*)&red[1][rr][e0];
    s += *(const f32x4*)&red[2][rr][e0];
    s += *(const f32x4*)&red[3][rr][e0];
    bf16x4 o;
#pragma unroll
    for (int j = 0; j < 4; j++) o[j] = (__bf16)s[j];
    *(bf16x4*)&st[rr][e0] = o;
  }
  __syncthreads();

  // ---- phase B: y = st @ w_out^T + LN; wave w = cols [w*256, w*256+256) ----
  bf16x8 ar[2];
  ar[0] = *(const bf16x8*)&st[fl][u * 8];
  ar[1] = *(const bf16x8*)&st[fl][32 + u * 8];

  const __bf16* wp = wob + (size_t)(w * 256 + fl) * 64 + u * 8;  // + ct*1024

  f32x4 acc[16] = {};
  bf16x8 bq[2][2];
  bq[0][0] = *(const bf16x8*)(wp);
  bq[0][1] = *(const bf16x8*)(wp + 32);

#pragma unroll
  for (int ct = 0; ct < 16; ct++) {
    const int p = ct & 1;
    if (ct < 15) {
      const __bf16* wpn = wp + (ct + 1) * 1024;
      bq[p ^ 1][0] = *(const bf16x8*)(wpn);
      bq[p ^ 1][1] = *(const bf16x8*)(wpn + 32);
    }
    acc[ct] = MFMA(ar[0], bq[p][0], acc[ct]);
    acc[ct] = MFMA(ar[1], bq[p][1], acc[ct]);
  }

  // LN partials over this wave's 256 cols (rows u*4+r)
  float s1[4], s2[4];
#pragma unroll
  for (int r = 0; r < 4; r++) {
    float a = 0.f, q = 0.f;
#pragma unroll
    for (int ct = 0; ct < 16; ct++) {
      const float v = acc[ct][r];
      a += v; q += v * v;
    }
    s1[r] = a; s2[r] = q;
  }
#pragma unroll
  for (int m = 1; m < 16; m <<= 1) {
#pragma unroll
    for (int r = 0; r < 4; r++) {
      s1[r] += __shfl_xor(s1[r], m, 64);
      s2[r] += __shfl_xor(s2[r], m, 64);
    }
  }
  if (fl == 0) {
#pragma unroll
    for (int r = 0; r < 4; r++) {
      pS1[w][u * 4 + r] = s1[r];
      pS2[w][u * 4 + r] = s2[r];
    }
  }
  __syncthreads();

  float mu[4], rs[4];
#pragma unroll
  for (int r = 0; r < 4; r++) {
    const int rl = u * 4 + r;
    const float S1 = pS1[0][rl] + pS1[1][rl] + pS1[2][rl] + pS1[3][rl];
    const float S2 = pS2[0][rl] + pS2[1][rl] + pS2[2][rl] + pS2[3][rl];
    const float m  = S1 * (1.0f / 1024.0f);
    const float va = S2 * (1.0f / 1024.0f) - m * m;
    mu[r] = m;
    rs[r] = rsqrtf(va + 1e-5f);
  }

#pragma unroll
  for (int ct = 0; ct < 16; ct++) {
    const int d = w * 256 + ct * 16 + fl;
    const float gv = gamma[d], bv = lbeta[d];
#pragma unroll
    for (int r = 0; r < 4; r++) {
      const float v = (acc[ct][r] - mu[r]) * rs[r] * gv + bv;
      y[(size_t)(rowbase + u * 4 + r) * 1024 + d] = v;
    }
  }
}

extern "C" void kernel_launch(void* const* d_in, const int* in_sizes, int n_in,
                              void* d_out, int out_size, void* d_ws, size_t ws_size,
                              hipStream_t stream) {
  const float* x         = (const float*)d_in[0];
  const float* alpha     = (const float*)d_in[1];
  const float* omega     = (const float*)d_in[2];
  const float* w_in      = (const float*)d_in[3];
  const float* w_out     = (const float*)d_in[4];
  const float* resonance = (const float*)d_in[5];
  const float* ln_g      = (const float*)d_in[6];
  const float* ln_b      = (const float*)d_in[7];
  float* out = (float*)d_out;

  char* ws = (char*)d_ws;
  __bf16* beta_bf = (__bf16*)ws;                                   // 2 MB
  __bf16* winb    = (__bf16*)(ws + (2u << 20));                    // 128 KB
  __bf16* wob     = (__bf16*)(ws + (2u << 20) + (128u << 10));     // 128 KB
  __bf16* Gt      = (__bf16*)(ws + (2u << 20) + (256u << 10));     // 128 KB
  float*  CkTR    = (float*) (ws + (2u << 20) + (384u << 10));     // 256 KB
  float*  CkTI    = (float*) (ws + (2u << 20) + (640u << 10));     // 256 KB

  k_su  <<<260,  256, 0, stream>>>(w_in, w_out, resonance, alpha, omega,
                                   winb, wob, Gt, CkTR, CkTI);
  k_b   <<<1024, 256, 0, stream>>>(x, winb, beta_bf);
  k_cfy <<<1032, 256, 0, stream>>>(beta_bf, Gt, wob, ln_g, ln_b, CkTR, CkTI, out);
}

// Round 7
// 74.348 us; speedup vs baseline: 1.9075x; 1.4634x over previous
//
#include <hip/hip_runtime.h>
#include <hip/hip_bf16.h>
#include <cstdint>
#include <cstddef>

typedef float  f32x4  __attribute__((ext_vector_type(4)));
typedef __bf16 bf16x8 __attribute__((ext_vector_type(8)));
typedef __bf16 bf16x4 __attribute__((ext_vector_type(4)));

#define MFMA(a, b, c) __builtin_amdgcn_mfma_f32_16x16x32_bf16((a), (b), (c), 0, 0, 0)

#define B_     8
#define S_     2048
#define D_     1024
#define E_     64
#define YSZ    (B_ * S_ * D_)   // 16777216
#define KTR    16               // truncation depth: rho^16 ~ 2e-7

// Fragment-permuted layouts (B-operand of mfma_f32_16x16x32_bf16):
//   frag(tile, kt) lane l elem j  <->  B[k][n], n = tile*16 + (l&15), k = kt*32 + (l>>4)*8 + j
// so a wave's fragment load is base + l*16B : one coalesced 1KB instruction.

// ---------------- k_su: permuted weight conversion (blocks 0..255) || impulse (256..259) ----------------
__global__ __launch_bounds__(256) void k_su(const float* __restrict__ w_in,
                                            const float* __restrict__ w_out,
                                            const float* __restrict__ resonance,
                                            const float* __restrict__ alpha,
                                            const float* __restrict__ omega,
                                            __bf16* __restrict__ winbF,
                                            __bf16* __restrict__ wobF,
                                            __bf16* __restrict__ GtF,
                                            float* __restrict__ CkTR,
                                            float* __restrict__ CkTI) {
  __shared__ __bf16 lsr[16][72];
  __shared__ __bf16 lsi[16][72];

  const int tid = threadIdx.x;

  if (blockIdx.x < 256) {
    const int i = blockIdx.x * 256 + tid;
    {
      // w_in[e][k] -> winbF frag(q = e>>4, kt = (k>>5)&1) at K-step kk = k>>6
      const int e = i >> 10, k = i & 1023;
      const int dst = ((k >> 5) * 4 + (e >> 4)) * 512 + ((k >> 3) & 3) * 128 + (e & 15) * 8 + (k & 7);
      winbF[dst] = (__bf16)w_in[i];
    }
    {
      // w_out[d][e] -> wobF frag(ct-tile d>>4, kt = e>>5)
      const int d = i >> 6, e = i & 63;
      const int dst = ((d >> 4) * 2 + (e >> 5)) * 512 + ((e >> 3) & 3) * 128 + (d & 15) * 8 + (e & 7);
      wobF[dst] = (__bf16)w_out[i];
    }
    return;
  }

  // ---- impulse: C_k = R(LambdaR)^k; one wave, 16 impulse columns per block ----
  if (tid >= 64) return;
  const int lane = tid;
  const int u = lane >> 4, fl = lane & 15;
  const int ecol = (blockIdx.x - 256) * 16 + fl;

  bf16x8 afr[4][2];   // A[f][e] = R[e][f] - (e==f)
#pragma unroll
  for (int mt = 0; mt < 4; mt++)
#pragma unroll
    for (int kt = 0; kt < 2; kt++)
#pragma unroll
      for (int j = 0; j < 8; j++) {
        const int e = kt * 32 + u * 8 + j;
        const int f = mt * 16 + fl;
        float v = resonance[e * 64 + f];
        if (e == f) v -= 1.0f;
        afr[mt][kt][j] = (__bf16)v;
      }

  float mcv[4][4], msv[4][4];
#pragma unroll
  for (int mt = 0; mt < 4; mt++)
#pragma unroll
    for (int r = 0; r < 4; r++) {
      const int fr = mt * 16 + u * 4 + r;
      const float mg = 1.0f / (1.0f + expf(-alpha[fr]));
      mcv[mt][r] = mg * cosf(omega[fr]);
      msv[mt][r] = mg * sinf(omega[fr]);
    }

  f32x4 sr[4] = {}, si[4] = {};

  for (int s = 0; s < KTR; s++) {
    f32x4 rr[4], ri[4];
#pragma unroll
    for (int mt = 0; mt < 4; mt++)
#pragma unroll
      for (int r = 0; r < 4; r++) {
        const float bt = (s == 0 && (mt * 16 + u * 4 + r) == ecol) ? 1.0f : 0.0f;
        rr[mt][r] = mcv[mt][r] * sr[mt][r] - msv[mt][r] * si[mt][r] + bt;
        ri[mt][r] = msv[mt][r] * sr[mt][r] + mcv[mt][r] * si[mt][r];
      }
#pragma unroll
    for (int mt = 0; mt < 4; mt++) {
      bf16x4 pr, pi;
#pragma unroll
      for (int r = 0; r < 4; r++) { pr[r] = (__bf16)rr[mt][r]; pi[r] = (__bf16)ri[mt][r]; }
      *(bf16x4*)&lsr[fl][mt * 16 + u * 4] = pr;
      *(bf16x4*)&lsi[fl][mt * 16 + u * 4] = pi;
    }
    // single wave: compiler lgkmcnt orders ds_write -> ds_read; no barrier needed
    bf16x8 brf[2], bif[2];
#pragma unroll
    for (int kt = 0; kt < 2; kt++) {
      brf[kt] = *(const bf16x8*)&lsr[fl][kt * 32 + u * 8];
      bif[kt] = *(const bf16x8*)&lsi[fl][kt * 32 + u * 8];
    }
#pragma unroll
    for (int mt = 0; mt < 4; mt++) {
      f32x4 dr = MFMA(afr[mt][0], brf[0], rr[mt]);
      sr[mt]   = MFMA(afr[mt][1], brf[1], dr);
      f32x4 di = MFMA(afr[mt][0], bif[0], ri[mt]);
      si[mt]   = MFMA(afr[mt][1], bif[1], di);
    }
    // state now equals C_s: store GtF (conv frag layout) + CkT ([k][e][f], fin)
#pragma unroll
    for (int mt = 0; mt < 4; mt++)
#pragma unroll
      for (int r = 0; r < 4; r++) {
        const int f = mt * 16 + u * 4 + r;
        GtF[((s * 2 + (ecol >> 5)) * 4 + mt) * 512 + ((ecol >> 3) & 3) * 128 + (u * 4 + r) * 8 + (ecol & 7)]
            = (__bf16)sr[mt][r];
        CkTR[s * 4096 + ecol * 64 + f] = sr[mt][r];
        CkTI[s * 4096 + ecol * 64 + f] = si[mt][r];
      }
  }
}

// ---------------- k_b: beta_bf = bf16(x @ w_in^T), LDS-staged A, frag-coalesced B ----------------
// 512 blocks x 256 thr (4 waves); block = 32 t-rows x 64 e, K = 1024 in 16 steps.
// Per step: x tile 32x64 f32 staged (coalesced 8x256B segs/inst) -> bf16 LDS (dbuf);
// B frags direct from winbF (1KB/inst). Wave = (rt = w&1: 16 rows, eh = w>>1: 32 e).
__global__ __launch_bounds__(256) void k_b(const float* __restrict__ x,
                                           const __bf16* __restrict__ winbF,
                                           __bf16* __restrict__ beta_bf) {
  __shared__ __bf16 lsA[2][32][72];

  const int tid = threadIdx.x;
  const int w = tid >> 6, lane = tid & 63;
  const int u = lane >> 4, fl = lane & 15;
  const int rt = w & 1, eh = w >> 1;
  const int rowbase = blockIdx.x * 32;

  const int srow = tid >> 3, scol = (tid & 7) * 8;
  const float* xs = x + (size_t)(rowbase + srow) * 1024 + scol;

  // prologue: stage step 0
  {
    const f32x4 c0 = *(const f32x4*)(xs);
    const f32x4 c1 = *(const f32x4*)(xs + 4);
    bf16x8 v;
#pragma unroll
    for (int j = 0; j < 4; j++) { v[j] = (__bf16)c0[j]; v[j + 4] = (__bf16)c1[j]; }
    *(bf16x8*)&lsA[0][srow][scol] = v;
  }
  __syncthreads();

  f32x4 acc[2] = {};
  int cur = 0;

#pragma unroll
  for (int kk = 0; kk < 16; kk++) {
    f32x4 n0, n1;
    if (kk < 15) {                       // issue next-step staging loads early
      n0 = *(const f32x4*)(xs + (kk + 1) * 64);
      n1 = *(const f32x4*)(xs + (kk + 1) * 64 + 4);
    }
    // B fragments: coalesced 1KB loads from winbF (L2-hot)
    bf16x8 b[2][2];
#pragma unroll
    for (int et = 0; et < 2; et++)
#pragma unroll
      for (int kt = 0; kt < 2; kt++)
        b[et][kt] = *(const bf16x8*)(winbF +
            (size_t)(((kk * 2 + kt) * 4 + eh * 2 + et) * 64 + lane) * 8);
    // A fragments from LDS (pad-72: 2-way bank aliasing, free)
    const bf16x8 a0 = *(const bf16x8*)&lsA[cur][rt * 16 + fl][u * 8];
    const bf16x8 a1 = *(const bf16x8*)&lsA[cur][rt * 16 + fl][32 + u * 8];
#pragma unroll
    for (int et = 0; et < 2; et++) {
      acc[et] = MFMA(a0, b[et][0], acc[et]);
      acc[et] = MFMA(a1, b[et][1], acc[et]);
    }
    if (kk < 15) {
      bf16x8 v;
#pragma unroll
      for (int j = 0; j < 4; j++) { v[j] = (__bf16)n0[j]; v[j + 4] = (__bf16)n1[j]; }
      *(bf16x8*)&lsA[cur ^ 1][srow][scol] = v;   // write other buffer
      __syncthreads();                           // one barrier per step (dbuf)
      cur ^= 1;
    }
  }

#pragma unroll
  for (int et = 0; et < 2; et++)
#pragma unroll
    for (int r = 0; r < 4; r++)
      beta_bf[(size_t)(rowbase + rt * 16 + u * 4 + r) * 64 + eh * 32 + et * 16 + fl]
          = (__bf16)acc[et][r];
}

// ---------------- k_cfy: conv (LDS halo + frag GtF) + y GEMM (frag wobF) + LN || fin ----------------
// 512 main blocks x 512 thr (8 waves); block = 32 t-rows x full D = 1024.
// Phase A: wave (rt = w>>2: 16 rows, fq = w&3: 16 f); A frags from halo LDS, B from GtF.
// Phase B: wave (rt, dq = w&3: 256 d); A frags from st LDS, B from wobF; LN across dq.
// Blocks 512..519: fin (r_fin/i_fin), coalesced CkT reads.
__global__ __launch_bounds__(512) void k_cfy(const __bf16* __restrict__ beta_bf,
                                             const __bf16* __restrict__ GtF,
                                             const __bf16* __restrict__ wobF,
                                             const float* __restrict__ gamma,
                                             const float* __restrict__ lbeta,
                                             const float* __restrict__ CkTR,
                                             const float* __restrict__ CkTI,
                                             float* __restrict__ y) {
  __shared__ __bf16 halo[48][72];
  __shared__ __bf16 st[32][72];
  __shared__ float pS1[8][16];
  __shared__ float pS2[8][16];

  const int tid = threadIdx.x;
  const int w = tid >> 6, lane = tid & 63;
  const int u = lane >> 4, fl = lane & 15;

  if (blockIdx.x >= 512) {
    // ---- fin: r_fin/i_fin = sum_k beta[2047-k] @ C_k ----
    if (tid >= 64) return;
    const int b = blockIdx.x - 512;
    const int f = tid;
    float aR = 0.f, aI = 0.f;
#pragma unroll
    for (int k = 0; k < KTR; k++) {
      const __bf16* br = beta_bf + (size_t)(b * S_ + (S_ - 1) - k) * 64;
      const float* cR = CkTR + k * 4096 + f;
      const float* cI = CkTI + k * 4096 + f;
#pragma unroll
      for (int e = 0; e < 64; e++) {
        const float bv = (float)br[e];   // wave-uniform -> broadcast
        aR += bv * cR[e * 64];           // lanes f contiguous -> coalesced
        aI += bv * cI[e * 64];
      }
    }
    y[YSZ + b * 64 + f]       = aR;
    y[YSZ + 512 + b * 64 + f] = aI;
    return;
  }

  const int rowbase = blockIdx.x * 32;
  const int tloc = rowbase & (S_ - 1);

  // ---- stage beta halo: rows rowbase-16 .. rowbase+31, zeroed before batch start ----
  if (tid < 384) {
    const int hr = tid >> 3, hc = (tid & 7) * 8;
    bf16x8 v = {};
    if (tloc - 16 + hr >= 0)
      v = *(const bf16x8*)(beta_bf + (size_t)(rowbase - 16 + hr) * 64 + hc);
    *(bf16x8*)&halo[hr][hc] = v;
  }
  __syncthreads();

  const int rt = w >> 2;

  // ---- phase A: conv over 16 lags; B frags coalesced from GtF ----
  {
    const int fq = w & 3;
    f32x4 acc1 = {};
#pragma unroll
    for (int k = 0; k < KTR; k++) {
      const bf16x8 b0 = *(const bf16x8*)(GtF + (size_t)(((k * 2 + 0) * 4 + fq) * 64 + lane) * 8);
      const bf16x8 b1 = *(const bf16x8*)(GtF + (size_t)(((k * 2 + 1) * 4 + fq) * 64 + lane) * 8);
      const int hrow = 16 + rt * 16 + fl - k;
      const bf16x8 a0 = *(const bf16x8*)&halo[hrow][u * 8];
      const bf16x8 a1 = *(const bf16x8*)&halo[hrow][32 + u * 8];
      acc1 = MFMA(a0, b0, acc1);
      acc1 = MFMA(a1, b1, acc1);
    }
#pragma unroll
    for (int r = 0; r < 4; r++)
      st[rt * 16 + u * 4 + r][fq * 16 + fl] = (__bf16)acc1[r];
  }
  __syncthreads();

  // ---- phase B: y = st @ w_out^T + LN ----
  const int dq = w & 3;
  const bf16x8 ar0 = *(const bf16x8*)&st[rt * 16 + fl][u * 8];
  const bf16x8 ar1 = *(const bf16x8*)&st[rt * 16 + fl][32 + u * 8];

  f32x4 acc[16] = {};
#pragma unroll
  for (int ct = 0; ct < 16; ct++) {
    const bf16x8 b0 = *(const bf16x8*)(wobF + (size_t)((((dq * 16 + ct) * 2 + 0) * 64) + lane) * 8);
    const bf16x8 b1 = *(const bf16x8*)(wobF + (size_t)((((dq * 16 + ct) * 2 + 1) * 64) + lane) * 8);
    acc[ct] = MFMA(ar0, b0, acc[ct]);
    acc[ct] = MFMA(ar1, b1, acc[ct]);
  }

  // LN partials over this wave's 256 cols (rows rt*16 + u*4 + r)
  float s1[4], s2[4];
#pragma unroll
  for (int r = 0; r < 4; r++) {
    float a = 0.f, q = 0.f;
#pragma unroll
    for (int ct = 0; ct < 16; ct++) {
      const float v = acc[ct][r];
      a += v; q += v * v;
    }
    s1[r] = a; s2[r] = q;
  }
#pragma unroll
  for (int m = 1; m < 16; m <<= 1) {
#pragma unroll
    for (int r = 0; r < 4; r++) {
      s1[r] += __shfl_xor(s1[r], m, 64);
      s2[r] += __shfl_xor(s2[r], m, 64);
    }
  }
  if (fl == 0) {
#pragma unroll
    for (int r = 0; r < 4; r++) {
      pS1[w][u * 4 + r] = s1[r];
      pS2[w][u * 4 + r] = s2[r];
    }
  }
  __syncthreads();

  float mu[4], rs[4];
#pragma unroll
  for (int r = 0; r < 4; r++) {
    const int rl = u * 4 + r;
    float S1 = 0.f, S2 = 0.f;
#pragma unroll
    for (int g = 0; g < 4; g++) { S1 += pS1[rt * 4 + g][rl]; S2 += pS2[rt * 4 + g][rl]; }
    const float m  = S1 * (1.0f / 1024.0f);
    const float va = S2 * (1.0f / 1024.0f) - m * m;
    mu[r] = m;
    rs[r] = rsqrtf(va + 1e-5f);
  }

#pragma unroll
  for (int ct = 0; ct < 16; ct++) {
    const int d = dq * 256 + ct * 16 + fl;
    const float gv = gamma[d], bv = lbeta[d];
#pragma unroll
    for (int r = 0; r < 4; r++) {
      const float v = (acc[ct][r] - mu[r]) * rs[r] * gv + bv;
      y[(size_t)(rowbase + rt * 16 + u * 4 + r) * 1024 + d] = v;
    }
  }
}

extern "C" void kernel_launch(void* const* d_in, const int* in_sizes, int n_in,
                              void* d_out, int out_size, void* d_ws, size_t ws_size,
                              hipStream_t stream) {
  const float* x         = (const float*)d_in[0];
  const float* alpha     = (const float*)d_in[1];
  const float* omega     = (const float*)d_in[2];
  const float* w_in      = (const float*)d_in[3];
  const float* w_out     = (const float*)d_in[4];
  const float* resonance = (const float*)d_in[5];
  const float* ln_g      = (const float*)d_in[6];
  const float* ln_b      = (const float*)d_in[7];
  float* out = (float*)d_out;

  char* ws = (char*)d_ws;
  __bf16* beta_bf = (__bf16*)ws;                                   // 2 MB
  __bf16* winbF   = (__bf16*)(ws + (2u << 20));                    // 128 KB
  __bf16* wobF    = (__bf16*)(ws + (2u << 20) + (128u << 10));     // 128 KB
  __bf16* GtF     = (__bf16*)(ws + (2u << 20) + (256u << 10));     // 128 KB
  float*  CkTR    = (float*) (ws + (2u << 20) + (384u << 10));     // 256 KB
  float*  CkTI    = (float*) (ws + (2u << 20) + (640u << 10));     // 256 KB

  k_su  <<<260, 256, 0, stream>>>(w_in, w_out, resonance, alpha, omega,
                                  winbF, wobF, GtF, CkTR, CkTI);
  k_b   <<<512, 256, 0, stream>>>(x, winbF, beta_bf);
  k_cfy <<<520, 512, 0, stream>>>(beta_bf, GtF, wobF, ln_g, ln_b, CkTR, CkTI, out);
}